// Round 1
// baseline (243.674 us; speedup 1.0000x reference)
//
#include <hip/hip_runtime.h>

typedef unsigned short u16;
typedef short short8 __attribute__((ext_vector_type(8)));
typedef float f32x4 __attribute__((ext_vector_type(4)));

static_assert(sizeof(short8) == 16, "short8 must be 16B");

// ---------- helpers ----------
__device__ __forceinline__ u16 f2bf(float f) {
  unsigned u = __float_as_uint(f);
  u += 0x7FFFu + ((u >> 16) & 1u);   // RNE
  return (u16)(u >> 16);
}
__device__ __forceinline__ float bf2f(u16 h) { return __uint_as_float(((unsigned)h) << 16); }

__device__ __forceinline__ f32x4 mfma_bf16(short8 a, short8 b, f32x4 c) {
  return __builtin_amdgcn_mfma_f32_16x16x32_bf16(a, b, c, 0, 0, 0);
}

__device__ __forceinline__ void gload_lds16(const void* g, void* l) {
  __builtin_amdgcn_global_load_lds((__attribute__((address_space(1))) void*)g,
                                   (__attribute__((address_space(3))) void*)l, 16, 0, 0);
}

// ---------- fp32 -> bf16 conversion (hidden + 4 weights) ----------
__global__ __launch_bounds__(256) void cvt_kernel(
    const float* __restrict__ hs, const float* __restrict__ wq, const float* __restrict__ wk,
    const float* __restrict__ wv, const float* __restrict__ wo,
    u16* __restrict__ hbf, u16* __restrict__ wbf) {
  const float* src; u16* dst; int n4;
  switch (blockIdx.y) {
    case 0:  src = hs; dst = hbf;            n4 = 786432; break;  // 4096*768/4
    case 1:  src = wq; dst = wbf;            n4 = 147456; break;  // 768*768/4
    case 2:  src = wk; dst = wbf + 589824;   n4 = 147456; break;
    case 3:  src = wv; dst = wbf + 1179648;  n4 = 147456; break;
    default: src = wo; dst = wbf + 1769472;  n4 = 147456; break;
  }
  int i = blockIdx.x * 256 + threadIdx.x;
  if (i >= n4) return;
  float4 v = ((const float4*)src)[i];
  uint2 r;
  r.x = (unsigned)f2bf(v.x) | ((unsigned)f2bf(v.y) << 16);
  r.y = (unsigned)f2bf(v.z) | ((unsigned)f2bf(v.w) << 16);
  ((uint2*)dst)[i] = r;
}

// ---------- RoPE, in-place on q and k ([B*H, S, 64] bf16) ----------
__global__ __launch_bounds__(256) void rope_kernel(u16* __restrict__ qb, u16* __restrict__ kb) {
  int idx = blockIdx.x * 256 + threadIdx.x;   // < 24*2048*32 = 1572864
  u16* buf = blockIdx.y ? kb : qb;
  int j = idx & 31;
  int sbh = idx >> 5;                         // bh*2048 + s
  int s = sbh & 2047;
  size_t base = (size_t)sbh * 64;
  float x1 = bf2f(buf[base + j]);
  float x2 = bf2f(buf[base + 32 + j]);
  float freq = __expf(-0.2878231366242557f * (float)j);  // 10000^(-j/32)
  float th = (float)s * freq;
  float sn, cs;
  __sincosf(th, &sn, &cs);
  buf[base + j]      = f2bf(x1 * cs - x2 * sn);
  buf[base + 32 + j] = f2bf(x2 * cs + x1 * sn);
}

// ---------- GEMM: C(MxN) = A(MxK) * B(NxK)^T, bf16 in, m97-style ----------
// MODE 0: QKV epilogue -> q[B,H,S,D], k[B,H,S,D], vt[B,H,D,S] (bf16)
// MODE 1: fp32 epilogue -> fout row-major (M x 768)
template <int MODE>
__global__ __launch_bounds__(256) void gemm_bt(
    const u16* __restrict__ A, const u16* __restrict__ Bm,
    u16* __restrict__ qb, u16* __restrict__ kb, u16* __restrict__ vtb,
    float* __restrict__ fout) {
  __shared__ char sA[16384];   // 128 rows x 64 bf16 (8 x 16B slots, XOR-swizzled)
  __shared__ char sB[16384];
  const int K = 768;
  const int t = threadIdx.x;
  const int lane = t & 63;
  const int w = t >> 6;              // wave 0..3
  const int wr = w >> 1, wc = w & 1; // 2x2 wave grid of 64x64 subtiles
  const int lrow = lane & 15, lkg = lane >> 4;
  const int arow0 = blockIdx.x * 128, brow0 = blockIdx.y * 128;

  f32x4 acc[4][4];
  const f32x4 z4 = {0.f, 0.f, 0.f, 0.f};
#pragma unroll
  for (int m = 0; m < 4; ++m)
#pragma unroll
    for (int n = 0; n < 4; ++n) acc[m][n] = z4;

  const int srow = t >> 3;   // 0..31 (staging row within 32-row chunk)
  const int sslot = t & 7;   // physical 16B slot

  for (int kt = 0; kt < K; kt += 64) {
    __syncthreads();
#pragma unroll
    for (int it = 0; it < 4; ++it) {
      int r = it * 32 + srow;
      int ls = sslot ^ (r & 7);   // inverse-swizzled global source slot
      gload_lds16(A + (size_t)(arow0 + r) * K + (kt + ls * 8), sA + it * 4096 + w * 1024);
      gload_lds16(Bm + (size_t)(brow0 + r) * K + (kt + ls * 8), sB + it * 4096 + w * 1024);
    }
    __syncthreads();
#pragma unroll
    for (int kk = 0; kk < 2; ++kk) {
      short8 af[4], bfr[4];
#pragma unroll
      for (int m = 0; m < 4; ++m) {
        int row = wr * 64 + m * 16 + lrow;
        int ph = (kk * 4 + lkg) ^ (row & 7);
        af[m] = *(const short8*)(sA + row * 128 + ph * 16);
      }
#pragma unroll
      for (int n = 0; n < 4; ++n) {
        int row = wc * 64 + n * 16 + lrow;
        int ph = (kk * 4 + lkg) ^ (row & 7);
        bfr[n] = *(const short8*)(sB + row * 128 + ph * 16);
      }
#pragma unroll
      for (int m = 0; m < 4; ++m)
#pragma unroll
        for (int n = 0; n < 4; ++n) acc[m][n] = mfma_bf16(af[m], bfr[n], acc[m][n]);
    }
  }

#pragma unroll
  for (int m = 0; m < 4; ++m) {
#pragma unroll
    for (int n = 0; n < 4; ++n) {
#pragma unroll
      for (int i = 0; i < 4; ++i) {
        int row = arow0 + wr * 64 + m * 16 + (lane >> 4) * 4 + i;
        int col = brow0 + wc * 64 + n * 16 + (lane & 15);
        float v = acc[m][n][i];
        if (MODE == 1) {
          fout[(size_t)row * 768 + col] = v;
        } else {
          int b = row >> 11, s = row & 2047;
          int qsel = col / 768;            // uniform per block (768 % 128 == 0)
          int oc = col - qsel * 768;
          int h = oc >> 6, d = oc & 63;
          size_t bh = (size_t)(b * 12 + h);
          u16 bv = f2bf(v);
          if (qsel == 0)      qb[(bh * 2048 + s) * 64 + d] = bv;
          else if (qsel == 1) kb[(bh * 2048 + s) * 64 + d] = bv;
          else                vtb[(bh * 64 + d) * 2048 + s] = bv;  // V transposed
        }
      }
    }
  }
}

// ---------- causal flash attention: 1 wave per 16 q-rows, kv tiles of 32 ----------
__global__ __launch_bounds__(256) void attn_fwd(
    const u16* __restrict__ qg, const u16* __restrict__ kg,
    const u16* __restrict__ vtg, u16* __restrict__ og) {
  __shared__ char psm[4 * 1280];   // per-wave P buffer: 16 rows x 80B (pad -> no conflicts)
  const int lane = threadIdx.x & 63;
  const int w = threadIdx.x >> 6;
  const int task = blockIdx.x * 4 + w;   // 0..3071
  const int qt = task & 127;
  const int bh = task >> 7;              // b*12+h
  const int qbase = qt * 16;
  const int lrow = lane & 15, lkg = lane >> 4;
  const u16* Q  = qg  + (size_t)bh * (2048 * 64);
  const u16* Kp = kg  + (size_t)bh * (2048 * 64);
  const u16* VT = vtg + (size_t)bh * (64 * 2048);
  char* pl = psm + w * 1280;

  short8 qf0 = *(const short8*)(Q + (qbase + lrow) * 64 + lkg * 8);
  short8 qf1 = *(const short8*)(Q + (qbase + lrow) * 64 + 32 + lkg * 8);

  const f32x4 z4 = {0.f, 0.f, 0.f, 0.f};
  f32x4 o0 = z4, o1 = z4, o2 = z4, o3 = z4;
  float m_[4], l_[4];
#pragma unroll
  for (int i = 0; i < 4; ++i) { m_[i] = -1e30f; l_[i] = 0.f; }

  const int kvend = qbase + 16;
  for (int kv0 = 0; kv0 < kvend; kv0 += 32) {
    const u16* Kt = Kp + (size_t)kv0 * 64;
    short8 k00 = *(const short8*)(Kt + lrow * 64 + lkg * 8);
    short8 k01 = *(const short8*)(Kt + lrow * 64 + 32 + lkg * 8);
    short8 k10 = *(const short8*)(Kt + (16 + lrow) * 64 + lkg * 8);
    short8 k11 = *(const short8*)(Kt + (16 + lrow) * 64 + 32 + lkg * 8);
    f32x4 s0 = z4, s1 = z4;
    s0 = mfma_bf16(qf0, k00, s0);  s0 = mfma_bf16(qf1, k01, s0);
    s1 = mfma_bf16(qf0, k10, s1);  s1 = mfma_bf16(qf1, k11, s1);

    float sv0[4], sv1[4];
#pragma unroll
    for (int i = 0; i < 4; ++i) { sv0[i] = s0[i] * 0.125f; sv1[i] = s1[i] * 0.125f; }
    if (kv0 + 32 > qbase) {   // causal tail tile
#pragma unroll
      for (int i = 0; i < 4; ++i) {
        int qr = qbase + lkg * 4 + i;
        if (kv0 + lrow > qr)      sv0[i] = -1e30f;
        if (kv0 + 16 + lrow > qr) sv1[i] = -1e30f;
      }
    }
    float mt[4];
#pragma unroll
    for (int i = 0; i < 4; ++i) mt[i] = fmaxf(sv0[i], sv1[i]);
#pragma unroll
    for (int off = 8; off >= 1; off >>= 1)
#pragma unroll
      for (int i = 0; i < 4; ++i) mt[i] = fmaxf(mt[i], __shfl_xor(mt[i], off));

    float scl[4], pr0[4], pr1[4], rs[4];
#pragma unroll
    for (int i = 0; i < 4; ++i) {
      float mn = fmaxf(m_[i], mt[i]);
      scl[i] = __expf(m_[i] - mn);
      m_[i] = mn;
      pr0[i] = __expf(sv0[i] - mn);
      pr1[i] = __expf(sv1[i] - mn);
      rs[i] = pr0[i] + pr1[i];
    }
#pragma unroll
    for (int off = 8; off >= 1; off >>= 1)
#pragma unroll
      for (int i = 0; i < 4; ++i) rs[i] += __shfl_xor(rs[i], off);
#pragma unroll
    for (int i = 0; i < 4; ++i) {
      l_[i] = l_[i] * scl[i] + rs[i];
      o0[i] *= scl[i]; o1[i] *= scl[i]; o2[i] *= scl[i]; o3[i] *= scl[i];
    }

    // P -> LDS (transpose C-layout to A-operand layout)
#pragma unroll
    for (int i = 0; i < 4; ++i) {
      int r = lkg * 4 + i;
      *(u16*)(pl + r * 80 + lrow * 2)      = f2bf(pr0[i]);
      *(u16*)(pl + r * 80 + 32 + lrow * 2) = f2bf(pr1[i]);
    }
    short8 pf = *(const short8*)(pl + lrow * 80 + lkg * 16);

    short8 v0 = *(const short8*)(VT + (size_t)(lrow) * 2048 + kv0 + lkg * 8);
    short8 v1 = *(const short8*)(VT + (size_t)(16 + lrow) * 2048 + kv0 + lkg * 8);
    short8 v2 = *(const short8*)(VT + (size_t)(32 + lrow) * 2048 + kv0 + lkg * 8);
    short8 v3 = *(const short8*)(VT + (size_t)(48 + lrow) * 2048 + kv0 + lkg * 8);
    o0 = mfma_bf16(pf, v0, o0);
    o1 = mfma_bf16(pf, v1, o1);
    o2 = mfma_bf16(pf, v2, o2);
    o3 = mfma_bf16(pf, v3, o3);
  }

  int b = bh / 12, h = bh - b * 12;
#pragma unroll
  for (int i = 0; i < 4; ++i) {
    float inv = 1.0f / l_[i];
    int qr = qbase + lkg * 4 + i;
    u16* orow = og + ((size_t)(b * 2048 + qr)) * 768 + h * 64;
    orow[lrow]      = f2bf(o0[i] * inv);
    orow[16 + lrow] = f2bf(o1[i] * inv);
    orow[32 + lrow] = f2bf(o2[i] * inv);
    orow[48 + lrow] = f2bf(o3[i] * inv);
  }
}

// ---------- launch ----------
extern "C" void kernel_launch(void* const* d_in, const int* in_sizes, int n_in,
                              void* d_out, int out_size, void* d_ws, size_t ws_size,
                              hipStream_t stream) {
  const float* hs = (const float*)d_in[0];
  const float* wq = (const float*)d_in[1];
  const float* wk = (const float*)d_in[2];
  const float* wv = (const float*)d_in[3];
  const float* wo = (const float*)d_in[4];
  // d_in[5] (attn_mask) is exactly causal -1e9: implemented in-kernel.
  float* out = (float*)d_out;
  char* ws = (char*)d_ws;

  u16* hbf = (u16*)(ws);               // 4096x768 bf16          (6291456 B)
  u16* wbf = (u16*)(ws + 6291456);     // wq|wk|wv|wo bf16       (4718592 B)
  u16* qb  = (u16*)(ws + 11010048);    // [B,H,S,64] bf16        (6291456 B)
  u16* kb  = (u16*)(ws + 17301504);    // [B,H,S,64] bf16        (6291456 B)
  u16* vtb = (u16*)(ws + 23592960);    // [B,H,64,S] bf16        (6291456 B)
  u16* ob  = (u16*)(ws + 29884416);    // [B,S,768]  bf16        (6291456 B)

  cvt_kernel<<<dim3(3072, 5), 256, 0, stream>>>(hs, wq, wk, wv, wo, hbf, wbf);
  gemm_bt<0><<<dim3(32, 18), 256, 0, stream>>>(hbf, wbf, qb, kb, vtb, nullptr);
  rope_kernel<<<dim3(6144, 2), 256, 0, stream>>>(qb, kb);
  attn_fwd<<<dim3(768), 256, 0, stream>>>(qb, kb, vtb, ob);
  gemm_bt<1><<<dim3(32, 6), 256, 0, stream>>>(ob, wbf + 1769472, nullptr, nullptr, nullptr, out);
}

// Round 2
// 167.833 us; speedup vs baseline: 1.4519x; 1.4519x over previous
//
#include <hip/hip_runtime.h>

typedef unsigned short u16;
typedef short short8 __attribute__((ext_vector_type(8)));
typedef float f32x4 __attribute__((ext_vector_type(4)));

static_assert(sizeof(short8) == 16, "short8 must be 16B");

// ---------- helpers ----------
__device__ __forceinline__ u16 f2bf(float f) {
  unsigned u = __float_as_uint(f);
  u += 0x7FFFu + ((u >> 16) & 1u);   // RNE
  return (u16)(u >> 16);
}
__device__ __forceinline__ float bf2f(u16 h) { return __uint_as_float(((unsigned)h) << 16); }

__device__ __forceinline__ f32x4 mfma_bf16(short8 a, short8 b, f32x4 c) {
  return __builtin_amdgcn_mfma_f32_16x16x32_bf16(a, b, c, 0, 0, 0);
}

__device__ __forceinline__ void gload_lds16(const void* g, void* l) {
  __builtin_amdgcn_global_load_lds((__attribute__((address_space(1))) void*)g,
                                   (__attribute__((address_space(3))) void*)l, 16, 0, 0);
}

// ---------- fp32 -> bf16 conversion (hidden + 4 weights) ----------
__global__ __launch_bounds__(256) void cvt_kernel(
    const float* __restrict__ hs, const float* __restrict__ wq, const float* __restrict__ wk,
    const float* __restrict__ wv, const float* __restrict__ wo,
    u16* __restrict__ hbf, u16* __restrict__ wbf) {
  const float* src; u16* dst; int n4;
  switch (blockIdx.y) {
    case 0:  src = hs; dst = hbf;            n4 = 786432; break;  // 4096*768/4
    case 1:  src = wq; dst = wbf;            n4 = 147456; break;  // 768*768/4
    case 2:  src = wk; dst = wbf + 589824;   n4 = 147456; break;
    case 3:  src = wv; dst = wbf + 1179648;  n4 = 147456; break;
    default: src = wo; dst = wbf + 1769472;  n4 = 147456; break;
  }
  int i = blockIdx.x * 256 + threadIdx.x;
  if (i >= n4) return;
  float4 v = ((const float4*)src)[i];
  uint2 r;
  r.x = (unsigned)f2bf(v.x) | ((unsigned)f2bf(v.y) << 16);
  r.y = (unsigned)f2bf(v.z) | ((unsigned)f2bf(v.w) << 16);
  ((uint2*)dst)[i] = r;
}

// ---------- RoPE, in-place on q and k ([B*H, S, 64] bf16) ----------
__global__ __launch_bounds__(256) void rope_kernel(u16* __restrict__ qb, u16* __restrict__ kb) {
  int idx = blockIdx.x * 256 + threadIdx.x;   // < 24*2048*32 = 1572864
  u16* buf = blockIdx.y ? kb : qb;
  int j = idx & 31;
  int sbh = idx >> 5;                         // bh*2048 + s
  int s = sbh & 2047;
  size_t base = (size_t)sbh * 64;
  float x1 = bf2f(buf[base + j]);
  float x2 = bf2f(buf[base + 32 + j]);
  float freq = __expf(-0.2878231366242557f * (float)j);  // 10000^(-j/32)
  float th = (float)s * freq;
  float sn, cs;
  __sincosf(th, &sn, &cs);
  buf[base + j]      = f2bf(x1 * cs - x2 * sn);
  buf[base + 32 + j] = f2bf(x2 * cs + x1 * sn);
}

// ---------- GEMM: C(MxN) = A(MxK) * B(NxK)^T, bf16 in, m97-style ----------
// MODE 0: QKV epilogue -> q[B,H,S,D], k[B,H,S,D], vt[B,H,D,S] (bf16)
// MODE 1: fp32 epilogue -> fout row-major (M x 768)
template <int MODE>
__global__ __launch_bounds__(256) void gemm_bt(
    const u16* __restrict__ A, const u16* __restrict__ Bm,
    u16* __restrict__ qb, u16* __restrict__ kb, u16* __restrict__ vtb,
    float* __restrict__ fout) {
  __shared__ char sA[16384];   // 128 rows x 64 bf16 (8 x 16B slots, XOR-swizzled)
  __shared__ char sB[16384];
  const int K = 768;
  const int t = threadIdx.x;
  const int lane = t & 63;
  const int w = t >> 6;              // wave 0..3
  const int wr = w >> 1, wc = w & 1; // 2x2 wave grid of 64x64 subtiles
  const int lrow = lane & 15, lkg = lane >> 4;
  const int arow0 = blockIdx.x * 128, brow0 = blockIdx.y * 128;

  f32x4 acc[4][4];
  const f32x4 z4 = {0.f, 0.f, 0.f, 0.f};
#pragma unroll
  for (int m = 0; m < 4; ++m)
#pragma unroll
    for (int n = 0; n < 4; ++n) acc[m][n] = z4;

  const int srow = t >> 3;   // 0..31 (staging row within 32-row chunk)
  const int sslot = t & 7;   // physical 16B slot

  for (int kt = 0; kt < K; kt += 64) {
    __syncthreads();
#pragma unroll
    for (int it = 0; it < 4; ++it) {
      int r = it * 32 + srow;
      int ls = sslot ^ (r & 7);   // inverse-swizzled global source slot
      gload_lds16(A + (size_t)(arow0 + r) * K + (kt + ls * 8), sA + it * 4096 + w * 1024);
      gload_lds16(Bm + (size_t)(brow0 + r) * K + (kt + ls * 8), sB + it * 4096 + w * 1024);
    }
    __syncthreads();
#pragma unroll
    for (int kk = 0; kk < 2; ++kk) {
      short8 af[4], bfr[4];
#pragma unroll
      for (int m = 0; m < 4; ++m) {
        int row = wr * 64 + m * 16 + lrow;
        int ph = (kk * 4 + lkg) ^ (row & 7);
        af[m] = *(const short8*)(sA + row * 128 + ph * 16);
      }
#pragma unroll
      for (int n = 0; n < 4; ++n) {
        int row = wc * 64 + n * 16 + lrow;
        int ph = (kk * 4 + lkg) ^ (row & 7);
        bfr[n] = *(const short8*)(sB + row * 128 + ph * 16);
      }
#pragma unroll
      for (int m = 0; m < 4; ++m)
#pragma unroll
        for (int n = 0; n < 4; ++n) acc[m][n] = mfma_bf16(af[m], bfr[n], acc[m][n]);
    }
  }

#pragma unroll
  for (int m = 0; m < 4; ++m) {
#pragma unroll
    for (int n = 0; n < 4; ++n) {
#pragma unroll
      for (int i = 0; i < 4; ++i) {
        int row = arow0 + wr * 64 + m * 16 + (lane >> 4) * 4 + i;
        int col = brow0 + wc * 64 + n * 16 + (lane & 15);
        float v = acc[m][n][i];
        if (MODE == 1) {
          fout[(size_t)row * 768 + col] = v;
        } else {
          int b = row >> 11, s = row & 2047;
          int qsel = col / 768;            // uniform per block (768 % 128 == 0)
          int oc = col - qsel * 768;
          int h = oc >> 6, d = oc & 63;
          size_t bh = (size_t)(b * 12 + h);
          u16 bv = f2bf(v);
          if (qsel == 0)      qb[(bh * 2048 + s) * 64 + d] = bv;
          else if (qsel == 1) kb[(bh * 2048 + s) * 64 + d] = bv;
          else                vtb[(bh * 64 + d) * 2048 + s] = bv;  // V transposed
        }
      }
    }
  }
}

// ---------- causal flash attention v2 ----------
// 256 blocks x 12 waves; 1 wave = one 16-row q-tile; causal-paired task map
// for perfect per-CU balance. KVBLK=64, register-rotated K/V prefetch.
__global__ __launch_bounds__(768, 3) void attn_fwd(
    const u16* __restrict__ qg, const u16* __restrict__ kg,
    const u16* __restrict__ vtg, u16* __restrict__ og) {
  __shared__ char psm[12 * 2560];   // per-wave P: 16 rows x 160B (16B-aligned stride)
  const int lane = threadIdx.x & 63;
  const int w = threadIdx.x >> 6;          // 0..11
  const int lrow = lane & 15, lkg = lane >> 4;
  char* pl = psm + w * 2560;

  const int p = blockIdx.x * 6 + (w % 6);  // 0..1535
  const int task = (w < 6) ? p : (3071 - p);
  const int qt = task & 127;
  const int bh = task >> 7;                // b*12+h
  const int qbase = qt * 16;

  const u16* Q  = qg  + (size_t)bh * (2048 * 64);
  const u16* Kp = kg  + (size_t)bh * (2048 * 64);
  const u16* VT = vtg + (size_t)bh * (64 * 2048);

  short8 qf0 = *(const short8*)(Q + (qbase + lrow) * 64 + lkg * 8);
  short8 qf1 = *(const short8*)(Q + (qbase + lrow) * 64 + 32 + lkg * 8);

  const f32x4 z4 = {0.f, 0.f, 0.f, 0.f};
  f32x4 o[4];
  float m_[4], l_[4];
#pragma unroll
  for (int i = 0; i < 4; ++i) { o[i] = z4; m_[i] = -1e30f; l_[i] = 0.f; }

  const int niter = (qbase + 16 + 63) >> 6;

  short8 kf[4][2], vf[4][2];
#pragma unroll
  for (int kb = 0; kb < 4; ++kb) {
#pragma unroll
    for (int h = 0; h < 2; ++h) {
      kf[kb][h] = *(const short8*)(Kp + (size_t)(kb * 16 + lrow) * 64 + h * 32 + lkg * 8);
      vf[kb][h] = *(const short8*)(VT + (size_t)(kb * 16 + lrow) * 2048 + h * 32 + lkg * 8);
    }
  }

  for (int it = 0; it < niter; ++it) {
    const int kv0 = it << 6;
    // ---- QK^T ----
    f32x4 s[4];
#pragma unroll
    for (int kb = 0; kb < 4; ++kb) {
      s[kb] = mfma_bf16(qf0, kf[kb][0], z4);
      s[kb] = mfma_bf16(qf1, kf[kb][1], s[kb]);
    }
    // ---- prefetch next K (in-place rotate; hides under softmax+PV) ----
    if (it + 1 < niter) {
      const u16* Kn = Kp + (size_t)(kv0 + 64) * 64;
#pragma unroll
      for (int kb = 0; kb < 4; ++kb)
#pragma unroll
        for (int h = 0; h < 2; ++h)
          kf[kb][h] = *(const short8*)(Kn + (size_t)(kb * 16 + lrow) * 64 + h * 32 + lkg * 8);
    }
    // ---- softmax (online) ----
#pragma unroll
    for (int kb = 0; kb < 4; ++kb)
#pragma unroll
      for (int i = 0; i < 4; ++i) s[kb][i] *= 0.125f;
    if (kv0 + 64 > qbase) {   // causal tail tile(s)
#pragma unroll
      for (int kb = 0; kb < 4; ++kb)
#pragma unroll
        for (int i = 0; i < 4; ++i) {
          int kva = kv0 + kb * 16 + lrow;
          int qa = qbase + lkg * 4 + i;
          if (kva > qa) s[kb][i] = -1e30f;
        }
    }
    float mt[4];
#pragma unroll
    for (int i = 0; i < 4; ++i)
      mt[i] = fmaxf(fmaxf(s[0][i], s[1][i]), fmaxf(s[2][i], s[3][i]));
#pragma unroll
    for (int off = 8; off >= 1; off >>= 1)
#pragma unroll
      for (int i = 0; i < 4; ++i) mt[i] = fmaxf(mt[i], __shfl_xor(mt[i], off));

    float scl[4], rs[4];
#pragma unroll
    for (int i = 0; i < 4; ++i) {
      float mn = fmaxf(m_[i], mt[i]);
      scl[i] = __expf(m_[i] - mn);
      m_[i] = mn;
      rs[i] = 0.f;
    }
    // exp + P->LDS write fused
#pragma unroll
    for (int kb = 0; kb < 4; ++kb)
#pragma unroll
      for (int i = 0; i < 4; ++i) {
        float pv = __expf(s[kb][i] - m_[i]);
        rs[i] += pv;
        *(u16*)(pl + (lkg * 4 + i) * 160 + (kb * 16 + lrow) * 2) = f2bf(pv);
      }
#pragma unroll
    for (int off = 8; off >= 1; off >>= 1)
#pragma unroll
      for (int i = 0; i < 4; ++i) rs[i] += __shfl_xor(rs[i], off);
#pragma unroll
    for (int i = 0; i < 4; ++i) {
      l_[i] = l_[i] * scl[i] + rs[i];
      o[0][i] *= scl[i]; o[1][i] *= scl[i]; o[2][i] *= scl[i]; o[3][i] *= scl[i];
    }

    short8 pf0 = *(const short8*)(pl + lrow * 160 + lkg * 16);
    short8 pf1 = *(const short8*)(pl + lrow * 160 + 64 + lkg * 16);

    // ---- PV ----
#pragma unroll
    for (int db = 0; db < 4; ++db) {
      o[db] = mfma_bf16(pf0, vf[db][0], o[db]);
      o[db] = mfma_bf16(pf1, vf[db][1], o[db]);
    }
    // ---- prefetch next V (hides under next QK+softmax) ----
    if (it + 1 < niter) {
      const u16* Vn = VT + kv0 + 64;
#pragma unroll
      for (int db = 0; db < 4; ++db)
#pragma unroll
        for (int h = 0; h < 2; ++h)
          vf[db][h] = *(const short8*)(Vn + (size_t)(db * 16 + lrow) * 2048 + h * 32 + lkg * 8);
    }
  }

  int b = bh / 12, h = bh - b * 12;
#pragma unroll
  for (int i = 0; i < 4; ++i) {
    float inv = 1.0f / l_[i];
    int qr = qbase + lkg * 4 + i;
    u16* orow = og + ((size_t)(b * 2048 + qr)) * 768 + h * 64;
    orow[lrow]      = f2bf(o[0][i] * inv);
    orow[16 + lrow] = f2bf(o[1][i] * inv);
    orow[32 + lrow] = f2bf(o[2][i] * inv);
    orow[48 + lrow] = f2bf(o[3][i] * inv);
  }
}

// ---------- launch ----------
extern "C" void kernel_launch(void* const* d_in, const int* in_sizes, int n_in,
                              void* d_out, int out_size, void* d_ws, size_t ws_size,
                              hipStream_t stream) {
  const float* hs = (const float*)d_in[0];
  const float* wq = (const float*)d_in[1];
  const float* wk = (const float*)d_in[2];
  const float* wv = (const float*)d_in[3];
  const float* wo = (const float*)d_in[4];
  // d_in[5] (attn_mask) is exactly causal -1e9: implemented in-kernel.
  float* out = (float*)d_out;
  char* ws = (char*)d_ws;

  u16* hbf = (u16*)(ws);               // 4096x768 bf16          (6291456 B)
  u16* wbf = (u16*)(ws + 6291456);     // wq|wk|wv|wo bf16       (4718592 B)
  u16* qb  = (u16*)(ws + 11010048);    // [B,H,S,64] bf16        (6291456 B)
  u16* kb  = (u16*)(ws + 17301504);    // [B,H,S,64] bf16        (6291456 B)
  u16* vtb = (u16*)(ws + 23592960);    // [B,H,64,S] bf16        (6291456 B)
  u16* ob  = (u16*)(ws + 29884416);    // [B,S,768]  bf16        (6291456 B)

  cvt_kernel<<<dim3(3072, 5), 256, 0, stream>>>(hs, wq, wk, wv, wo, hbf, wbf);
  gemm_bt<0><<<dim3(32, 18), 256, 0, stream>>>(hbf, wbf, qb, kb, vtb, nullptr);
  rope_kernel<<<dim3(6144, 2), 256, 0, stream>>>(qb, kb);
  attn_fwd<<<dim3(256), 768, 0, stream>>>(qb, kb, vtb, ob);
  gemm_bt<1><<<dim3(32, 6), 256, 0, stream>>>(ob, wbf + 1769472, nullptr, nullptr, nullptr, out);
}